// Round 1
// 799.866 us; speedup vs baseline: 1.4494x; 1.4494x over previous
//
#include <hip/hip_runtime.h>
#include <math.h>

#define N_NODES 50000
#define N_EDGES 400000
#define FEAT    128
#define OUTF    384
#define N_RBF   20
#define CUTOFF  5.0f
#define PI_F    3.14159265358979f

__device__ __forceinline__ float silu_f(float x) { return x / (1.f + __expf(-x)); }

// ---------------------------------------------------------------------------
// Node kernel: phi = silu(s_j @ W1 + b1) @ W2 + b2     (50000 x 384)
// 64 nodes per block, 256 threads. Register tile 8 rows x 4 cols per thread.
// A^T and H^T share one 34 KB LDS buffer (pad 68 keeps float4 alignment and
// breaks the 32-bank stride). LDS traffic: 2 x ds_read_b128 per 32 FMAs.
// ---------------------------------------------------------------------------
constexpr int TM   = 64;   // nodes per block
constexpr int TPAD = 68;   // padded row length (floats): 68*4 B = 17*16 B

__global__ __launch_bounds__(256) void node_kernel(
    const float* __restrict__ s_j,
    const float* __restrict__ W1, const float* __restrict__ b1,
    const float* __restrict__ W2, const float* __restrict__ b2,
    float* __restrict__ phi)
{
    __shared__ float T[FEAT * TPAD];   // 34 KB: A^T, then reused as H^T

    const int tid   = threadIdx.x;
    const int node0 = blockIdx.x * TM;

    // ---- stage s_j tile transposed: T[f][r] (coalesced global read) ----
    for (int i = tid; i < TM * FEAT; i += 256) {
        int r = i >> 7, f = i & 127;
        float v = (node0 + r < N_NODES) ? s_j[(size_t)node0 * FEAT + i] : 0.f;
        T[f * TPAD + r] = v;
    }
    __syncthreads();

    const int cg = tid & 31;   // column group: cols cg*4 .. cg*4+3
    const int rg = tid >> 5;   // row group:    rows rg*8 .. rg*8+7
    const int c0 = cg * 4;
    const int r0 = rg * 8;

    // ---- GEMM 1: h = silu(A @ W1 + b1) ----
    float4 bv = *(const float4*)&b1[c0];
    float acc[8][4];
#pragma unroll
    for (int i = 0; i < 8; ++i) { acc[i][0] = bv.x; acc[i][1] = bv.y; acc[i][2] = bv.z; acc[i][3] = bv.w; }

#pragma unroll 4
    for (int k = 0; k < FEAT; ++k) {
        float4 a0 = *(const float4*)&T[k * TPAD + r0];       // LDS broadcast
        float4 a1 = *(const float4*)&T[k * TPAD + r0 + 4];
        float4 w  = *(const float4*)&W1[k * FEAT + c0];      // L1-resident, coalesced
        const float av[8] = {a0.x, a0.y, a0.z, a0.w, a1.x, a1.y, a1.z, a1.w};
        const float wv[4] = {w.x, w.y, w.z, w.w};
#pragma unroll
        for (int i = 0; i < 8; ++i)
#pragma unroll
            for (int j = 0; j < 4; ++j)
                acc[i][j] = fmaf(av[i], wv[j], acc[i][j]);
    }
    __syncthreads();   // all A^T reads complete before overwrite

    // ---- silu + store H^T into the same buffer ----
#pragma unroll
    for (int j = 0; j < 4; ++j) {
        *(float4*)&T[(c0 + j) * TPAD + r0] =
            make_float4(silu_f(acc[0][j]), silu_f(acc[1][j]), silu_f(acc[2][j]), silu_f(acc[3][j]));
        *(float4*)&T[(c0 + j) * TPAD + r0 + 4] =
            make_float4(silu_f(acc[4][j]), silu_f(acc[5][j]), silu_f(acc[6][j]), silu_f(acc[7][j]));
    }
    __syncthreads();

    // ---- GEMM 2: phi = H @ W2 + b2  (384 cols in 3 chunks of 128) ----
    for (int ch = 0; ch < 3; ++ch) {
        const int cc = ch * 128 + c0;
        float4 b2v = *(const float4*)&b2[cc];
        float a2[8][4];
#pragma unroll
        for (int i = 0; i < 8; ++i) { a2[i][0] = b2v.x; a2[i][1] = b2v.y; a2[i][2] = b2v.z; a2[i][3] = b2v.w; }

#pragma unroll 4
        for (int k = 0; k < FEAT; ++k) {
            float4 h0 = *(const float4*)&T[k * TPAD + r0];
            float4 h1 = *(const float4*)&T[k * TPAD + r0 + 4];
            float4 w  = *(const float4*)&W2[k * OUTF + cc];
            const float hv[8] = {h0.x, h0.y, h0.z, h0.w, h1.x, h1.y, h1.z, h1.w};
            const float wv[4] = {w.x, w.y, w.z, w.w};
#pragma unroll
            for (int i = 0; i < 8; ++i)
#pragma unroll
                for (int j = 0; j < 4; ++j)
                    a2[i][j] = fmaf(hv[i], wv[j], a2[i][j]);
        }
#pragma unroll
        for (int i = 0; i < 8; ++i) {
            int g = node0 + r0 + i;
            if (g < N_NODES)
                *(float4*)&phi[(size_t)g * OUTF + cc] =
                    make_float4(a2[i][0], a2[i][1], a2[i][2], a2[i][3]);
        }
    }
}

// ---------------------------------------------------------------------------
// Edge kernel: out[e, j] = phi[nbrs[e,1], j] * (env*bd[j] + sum_n srbf[e,n]*Wd[n,j])
// 64 edges / 256 threads per block. Thread owns cols {c, c+128, c+256} and
// 32 edges (4 at a time). Wd slice (20x3) hoisted to registers; srbf stored
// transposed [n][e] and read as float4 broadcasts (1 LDS inst per 12 FMAs).
// Gather loads issued before the dot; nontemporal stores protect phi in L3.
// ---------------------------------------------------------------------------
constexpr int EPB = 64;   // N_EDGES % EPB == 0 -> no tail guard

__global__ __launch_bounds__(256) void edge_kernel(
    const float* __restrict__ dist,
    const int*   __restrict__ nbrs,
    const float* __restrict__ Wd, const float* __restrict__ bd,
    const float* __restrict__ phi,
    float* __restrict__ out)
{
    __shared__ float srbfT[N_RBF][EPB];   // 5 KB, env/d folded, transposed
    __shared__ float senv[EPB];
    __shared__ int   sidx[EPB];

    const int tid = threadIdx.x;
    const int e0  = blockIdx.x * EPB;

    if (tid < EPB) {
        const int e = e0 + tid;
        const float d = dist[e];
        sidx[tid] = nbrs[2 * e + 1];
        const float env = (d < CUTOFF) ? 0.5f * (__cosf(PI_F * d * (1.0f / CUTOFF)) + 1.f) : 0.f;
        senv[tid] = env;
        const float inv = (d == 0.f) ? 0.f : (env / d);
        const float w0 = PI_F * (1.0f / CUTOFF);
#pragma unroll
        for (int n = 0; n < N_RBF; ++n)
            srbfT[n][tid] = __sinf((float)(n + 1) * w0 * d) * inv;
    }

    const int c  = tid & 127;   // cols c, c+128, c+256 (stores stay coalesced)
    const int eg = tid >> 7;    // edge half: 32 edges

    // hoist the loop-invariant Wd slice + bd into registers (L1-resident reads)
    float wd[N_RBF][3];
#pragma unroll
    for (int n = 0; n < N_RBF; ++n) {
        wd[n][0] = Wd[n * OUTF + c];
        wd[n][1] = Wd[n * OUTF + c + 128];
        wd[n][2] = Wd[n * OUTF + c + 256];
    }
    const float bd0 = bd[c], bd1 = bd[c + 128], bd2 = bd[c + 256];

    __syncthreads();

    const int ebase = eg * 32;
#pragma unroll 1
    for (int g = 0; g < 8; ++g) {
        const int e4 = ebase + g * 4;

        // issue the 12 gather loads early; the 240 FMAs below hide the latency
        float ph[4][3];
#pragma unroll
        for (int i = 0; i < 4; ++i) {
            const float* pb = phi + (size_t)sidx[e4 + i] * OUTF;
            ph[i][0] = pb[c];
            ph[i][1] = pb[c + 128];
            ph[i][2] = pb[c + 256];
        }

        float acc[4][3];
#pragma unroll
        for (int i = 0; i < 4; ++i) {
            const float ev = senv[e4 + i];
            acc[i][0] = ev * bd0; acc[i][1] = ev * bd1; acc[i][2] = ev * bd2;
        }
#pragma unroll
        for (int n = 0; n < N_RBF; ++n) {
            const float4 rb = *(const float4*)&srbfT[n][e4];   // broadcast b128
            const float rv[4] = {rb.x, rb.y, rb.z, rb.w};
#pragma unroll
            for (int i = 0; i < 4; ++i) {
                acc[i][0] = fmaf(rv[i], wd[n][0], acc[i][0]);
                acc[i][1] = fmaf(rv[i], wd[n][1], acc[i][1]);
                acc[i][2] = fmaf(rv[i], wd[n][2], acc[i][2]);
            }
        }

#pragma unroll
        for (int i = 0; i < 4; ++i) {
            const size_t ob = (size_t)(e0 + e4 + i) * OUTF;
            __builtin_nontemporal_store(ph[i][0] * acc[i][0], &out[ob + c]);
            __builtin_nontemporal_store(ph[i][1] * acc[i][1], &out[ob + c + 128]);
            __builtin_nontemporal_store(ph[i][2] * acc[i][2], &out[ob + c + 256]);
        }
    }
}

// ---------------------------------------------------------------------------
extern "C" void kernel_launch(void* const* d_in, const int* in_sizes, int n_in,
                              void* d_out, int out_size, void* d_ws, size_t ws_size,
                              hipStream_t stream)
{
    const float* s_j  = (const float*)d_in[0];
    const float* dist = (const float*)d_in[1];
    const int*   nbrs = (const int*)  d_in[2];
    const float* W1   = (const float*)d_in[3];
    const float* b1   = (const float*)d_in[4];
    const float* W2   = (const float*)d_in[5];
    const float* b2   = (const float*)d_in[6];
    const float* Wd   = (const float*)d_in[7];
    const float* bd   = (const float*)d_in[8];

    float* out = (float*)d_out;
    float* phi = (float*)d_ws;    // 50000*384*4 = 76.8 MB scratch

    node_kernel<<<(N_NODES + TM - 1) / TM, 256, 0, stream>>>(s_j, W1, b1, W2, b2, phi);
    edge_kernel<<<N_EDGES / EPB, 256, 0, stream>>>(dist, nbrs, Wd, bd, phi, out);
}